// Round 3
// baseline (484.673 us; speedup 1.0000x reference)
//
#include <hip/hip_runtime.h>
#include <math.h>

#define N_NODES 50000
#define N_EDGES 800000
#define DIM 256
#define HEADS 8
#define DIM_OUT 32
#define INNER 256        // HEADS*DIM_OUT
#define M_PAD 50048      // 391 * 128

typedef __attribute__((ext_vector_type(8))) short bf16x8;
typedef __attribute__((ext_vector_type(4))) float f32x4;
typedef __attribute__((ext_vector_type(2))) float f32x2;

// round-to-nearest-even f32 -> bf16 bits
__device__ __forceinline__ unsigned short f2bf(float f) {
    unsigned u = __float_as_uint(f);
    unsigned r = (u + 0x7FFFu + ((u >> 16) & 1u)) >> 16;
    return (unsigned short)r;
}

// unpack uint (2 packed bf16) -> f32x2
__device__ __forceinline__ f32x2 up2(unsigned u) {
    f32x2 r;
    r.x = __uint_as_float(u << 16);
    r.y = __uint_as_float(u & 0xFFFF0000u);
    return r;
}
__device__ __forceinline__ void up2x4(uint4 r, f32x2* o) {
    o[0] = up2(r.x); o[1] = up2(r.y); o[2] = up2(r.z); o[3] = up2(r.w);
}

// global -> LDS direct copy, 16 B per lane, dest = wave-uniform base + lane*16
__device__ __forceinline__ void gll16(const void* g, void* l) {
    __builtin_amdgcn_global_load_lds(
        (const __attribute__((address_space(1))) unsigned*)(uintptr_t)g,
        (__attribute__((address_space(3))) unsigned*)(unsigned)(uintptr_t)l,
        16, 0, 0);
}

// ---------------------------------------------------------------------------
// prep: conv_x (6256 blocks) + conv_w (768) + deg_hist (3125), one dispatch.
// ---------------------------------------------------------------------------
#define NB_CONVX 6256   // M_PAD*256/8/256
#define NB_CONVW 768    // 3*65536/256
#define NB_HIST  3125   // N_EDGES/256
__global__ __launch_bounds__(256) void prep(
    const float* __restrict__ x,
    const float* __restrict__ Wq, const float* __restrict__ Wk,
    const float* __restrict__ Wv,
    const int* __restrict__ dst,
    unsigned short* __restrict__ xbf, unsigned short* __restrict__ Wt,
    int* __restrict__ deg)
{
    int b = blockIdx.x;
    if (b < NB_CONVX) {
        size_t i8 = ((size_t)b * 256 + threadIdx.x) * 8;
        unsigned short h[8];
        if (i8 < (size_t)N_NODES * 256) {
            float4 a = *(const float4*)(x + i8);
            float4 c = *(const float4*)(x + i8 + 4);
            h[0]=f2bf(a.x); h[1]=f2bf(a.y); h[2]=f2bf(a.z); h[3]=f2bf(a.w);
            h[4]=f2bf(c.x); h[5]=f2bf(c.y); h[6]=f2bf(c.z); h[7]=f2bf(c.w);
        } else {
            #pragma unroll
            for (int j = 0; j < 8; j++) h[j] = 0;
        }
        uint4 o;
        o.x = (unsigned)h[0] | ((unsigned)h[1] << 16);
        o.y = (unsigned)h[2] | ((unsigned)h[3] << 16);
        o.z = (unsigned)h[4] | ((unsigned)h[5] << 16);
        o.w = (unsigned)h[6] | ((unsigned)h[7] << 16);
        *(uint4*)(xbf + i8) = o;
    } else if (b < NB_CONVX + NB_CONVW) {
        int idx = (b - NB_CONVX) * 256 + threadIdx.x;   // < 3*65536
        int z = idx >> 16, r = idx & 65535;
        int k = r >> 8, n = r & 255;
        const float* W = (z == 0) ? Wq : (z == 1) ? Wk : Wv;
        Wt[(size_t)z * 65536 + n * 256 + k] = f2bf(W[k * 256 + n]);
    } else {
        int e = (b - NB_CONVX - NB_CONVW) * 256 + threadIdx.x;
        if (e < N_EDGES) atomicAdd(deg + dst[e], 1);
    }
}

// ---------------------------------------------------------------------------
// Fused QKV GEMM, BK=64: 4 K-steps (halves the vmcnt(0)+barrier drains vs
// BK=32; m233: that drain is the 2-phase critical path). LDS 32 KB -> 5
// blocks/CU. Linear LDS kept: LDS-read bank conflicts are hidden at 2-phase
// (m230). XCD-chunked bijective remap (m204) keeps the 6 blocks sharing an
// A row-panel on one XCD's L2.
// Block GEMM_NWG (one extra) runs the rowptr scan concurrently -> its ~10 us
// hide under the GEMM (scan needs only deg from prep; gemm only xbf/Wt).
// ---------------------------------------------------------------------------
#define GEMM_NWG 2346   // 391 * 2 * 3
__global__ __launch_bounds__(256) void gemm_qkv(
    const unsigned short* __restrict__ xbf,
    const unsigned short* __restrict__ Wt,   // [3][n][k] bf16
    const float* __restrict__ bq, const float* __restrict__ bk,
    const float* __restrict__ bv,
    unsigned short* __restrict__ q, unsigned short* __restrict__ k,
    unsigned short* __restrict__ v,
    const int* __restrict__ deg, int* __restrict__ rowptr)
{
    const int t = threadIdx.x;

    if (blockIdx.x == GEMM_NWG) {
        // ---- embedded single-block scan (256 threads, 1024-int tiles) ----
        __shared__ int wsum4[4];
        __shared__ int wpre4[5];
        int wid = t >> 6, ln = t & 63;
        int carry = 0;
        for (int base = 0; base < N_NODES; base += 1024) {
            int i4 = base + t * 4;
            int4 dv = {0, 0, 0, 0};
            if (i4 < N_NODES) dv = *(const int4*)(deg + i4);  // N_NODES%4==0
            int sum = dv.x + dv.y + dv.z + dv.w;
            int inc = sum;
            #pragma unroll
            for (int off = 1; off < 64; off <<= 1) {
                int u = __shfl_up(inc, off);
                if (ln >= off) inc += u;
            }
            if (ln == 63) wsum4[wid] = inc;
            __syncthreads();
            if (t == 0) {
                int a = 0;
                #pragma unroll
                for (int j = 0; j < 4; j++) { wpre4[j] = a; a += wsum4[j]; }
                wpre4[4] = a;
            }
            __syncthreads();
            if (i4 < N_NODES) {
                int r = carry + wpre4[wid] + (inc - sum);
                r += dv.x; rowptr[i4 + 1] = r;
                r += dv.y; rowptr[i4 + 2] = r;
                r += dv.z; rowptr[i4 + 3] = r;
                r += dv.w; rowptr[i4 + 4] = r;
            }
            carry += wpre4[4];
            __syncthreads();        // protect wsum4 for next tile
        }
        if (t == 0) rowptr[0] = 0;
        return;
    }

    // XCD-chunked bijective remap (nwg=2346: q8=293, r8=2)
    int hw = blockIdx.x;
    int xcd = hw & 7, pos = hw >> 3;
    const int q8 = GEMM_NWG >> 3, r8 = GEMM_NWG & 7;
    int lid = (xcd < r8 ? xcd * (q8 + 1) : r8 * (q8 + 1) + (xcd - r8) * q8) + pos;
    int xx = lid / 6;               // A row-panel index (slowest)
    int yz = lid - xx * 6;
    const int row0 = xx * 128;
    const int col0 = (yz & 1) * 128;
    const int z = yz >> 1;

    const unsigned short* Wz = Wt + (size_t)z * 65536;
    const float* bias = (z == 0) ? bq : (z == 1) ? bk : bv;
    unsigned short* C = (z == 0) ? q : (z == 1) ? k : v;

    __shared__ __align__(16) short As[128 * 64];   // 16 KB
    __shared__ __align__(16) short Bs[128 * 64];   // 16 KB

    const int wave = t >> 6;
    const int lane = t & 63;
    const int wm = (wave & 1) * 64;
    const int wn = (wave >> 1) * 64;
    const int lr = lane & 15;
    const int lg = lane >> 4;
    const int srow = lane >> 3;       // staging: row within 8-row segment
    const int sch  = lane & 7;        // staging: 16-B chunk within row (8x16B=128B row)

    f32x4 acc[4][4] = {};

    for (int k0 = 0; k0 < 256; k0 += 64) {
        // A: 128 rows x 64 k; 16 segments of 8 rows; wave w does segs 4w..4w+3
        #pragma unroll
        for (int c = 0; c < 4; c++) {
            int seg = wave * 4 + c;
            gll16(xbf + (size_t)(row0 + seg * 8 + srow) * 256 + k0 + sch * 8,
                  As + seg * 512);      // 512 shorts = 8 rows * 64
        }
        #pragma unroll
        for (int c = 0; c < 4; c++) {
            int seg = wave * 4 + c;
            gll16(Wz + (size_t)(col0 + seg * 8 + srow) * 256 + k0 + sch * 8,
                  Bs + seg * 512);
        }
        __syncthreads();   // vmcnt(0) drain + barrier (once per 64 k now)

        #pragma unroll
        for (int kk = 0; kk < 64; kk += 32) {
            bf16x8 af[4], bfr[4];
            #pragma unroll
            for (int mi = 0; mi < 4; mi++)
                af[mi] = *(const bf16x8*)&As[(wm + mi * 16 + lr) * 64 + kk + lg * 8];
            #pragma unroll
            for (int ni = 0; ni < 4; ni++)
                bfr[ni] = *(const bf16x8*)&Bs[(wn + ni * 16 + lr) * 64 + kk + lg * 8];
            #pragma unroll
            for (int mi = 0; mi < 4; mi++)
                #pragma unroll
                for (int ni = 0; ni < 4; ni++)
                    acc[mi][ni] = __builtin_amdgcn_mfma_f32_16x16x32_bf16(
                        af[mi], bfr[ni], acc[mi][ni], 0, 0, 0);
        }
        __syncthreads();
    }

    // epilogue: C/D layout col=lane&15, row=(lane>>4)*4+reg  [m89-verified]
    #pragma unroll
    for (int mi = 0; mi < 4; mi++) {
        #pragma unroll
        for (int ni = 0; ni < 4; ni++) {
            int gcol = col0 + wn + ni * 16 + lr;
            float bb = bias[gcol];
            #pragma unroll
            for (int r = 0; r < 4; r++) {
                int grow = row0 + wm + mi * 16 + lg * 4 + r;
                if (grow < N_NODES)
                    C[(size_t)grow * 256 + gcol] = f2bf(acc[mi][ni][r] + bb);
            }
        }
    }
}

// csr_scatter consumes deg via atomicSub (deg dead after scan).
// Payload is src[e] directly — node_attn then needs NO src[] indirection.
__global__ __launch_bounds__(256) void csr_scatter(
    const int* __restrict__ src, const int* __restrict__ dst,
    const int* __restrict__ rowptr,
    int* __restrict__ deg, int* __restrict__ edge_src)
{
    int e = blockIdx.x * 256 + threadIdx.x;
    if (e >= N_EDGES) return;
    int d = dst[e];
    int old = atomicSub(deg + d, 1);      // old in [1..degree]
    edge_src[rowptr[d] + old - 1] = src[e];
}

// ---------------------------------------------------------------------------
// Fused single-pass attention per dst node. One wave per node, half-wave per
// edge stream (32 lanes x 8 bf16 = 256 dims). Flash-style online softmax in
// exp2 domain. Wave-uniform counted loop (R2).
//
// R3: period-4 rotation (4 row-buffer pairs): rows loaded 3 bodies ahead,
// src ids fetched 4 bodies before their row-load. In-flight rows per wave
// 2 -> 3; __launch_bounds__(256,7) holds >=7 waves/SIMD -> +30% MLP.
// ---------------------------------------------------------------------------
__global__ __launch_bounds__(256, 7) void node_attn(
    const unsigned short* __restrict__ qbf,
    const unsigned short* __restrict__ kbf,
    const unsigned short* __restrict__ vbf,
    const int* __restrict__ rowptr, const int* __restrict__ edge_src,
    float* __restrict__ out)
{
    int node = blockIdx.x * 4 + (threadIdx.x >> 6);
    int lane = threadIdx.x & 63;
    if (node >= N_NODES) return;
    const int half = lane >> 5;
    const int l = lane & 31;

    int beg = rowptr[node], end = rowptr[node + 1];
    int deg = end - beg;

    float* op = out + (size_t)node * 256 + l * 8;
    if (deg <= 0) {               // no incoming edges -> zeros (matches ref)
        if (half == 0) {
            float4 z4 = {0.f, 0.f, 0.f, 0.f};
            *(float4*)op = z4;
            *(float4*)(op + 4) = z4;
        }
        return;
    }

    f32x2 kf2[4];
    up2x4(*(const uint4*)(kbf + (size_t)node * 256 + l * 8), kf2);

    const unsigned short* qrow = qbf + l * 8;   // + id*256 shorts per edge
    const unsigned short* vrow = vbf + l * 8;

    // 1/sqrt(32) * log2(e): softmax runs in exp2 domain (ratios exact)
    const float SC = 0.17677669529663687f * 1.4426950408889634f;

    int U = (deg + 1) >> 1;            // slots per half (half1 may have -1)
    U = ((U + 3) >> 2) << 2;           // round up to unroll factor 4
    U = __builtin_amdgcn_readfirstlane(U);   // wave-uniform -> scalar loop

    const int i0 = beg + half;         // this half's stream, stride 2
    const int last = end - 1;          // clamp target (valid: deg >= 1)

    // ramp: rows for slots 0,1,2; ids for slots 3..6
    int t0  = edge_src[min(i0,      last)];
    int t1  = edge_src[min(i0 + 2,  last)];
    int t2  = edge_src[min(i0 + 4,  last)];
    int id3 = edge_src[min(i0 + 6,  last)];
    int id4 = edge_src[min(i0 + 8,  last)];
    int id5 = edge_src[min(i0 + 10, last)];
    int id6 = edge_src[min(i0 + 12, last)];
    uint4 qA = *(const uint4*)(qrow + (size_t)t0 * 256);
    uint4 vA = *(const uint4*)(vrow + (size_t)t0 * 256);
    uint4 qB = *(const uint4*)(qrow + (size_t)t1 * 256);
    uint4 vB = *(const uint4*)(vrow + (size_t)t1 * 256);
    uint4 qC = *(const uint4*)(qrow + (size_t)t2 * 256);
    uint4 vC = *(const uint4*)(vrow + (size_t)t2 * 256);
    uint4 qD = {}, vD = {};

    float m = -1e30f, zsum = 0.0f;
    f32x2 af2[4] = {};

// body for slot t+P: compute from (QW,VW); load rows of slot t+P+3 into
// (QL,VL) via IDR; then refetch IDR with the id of slot t+P+7 (consumed
// 4 bodies later).
#define BODY(QW, VW, QL, VL, IDR, P)                                         \
    do {                                                                     \
        size_t off_ = (size_t)(IDR) * 256;                                   \
        QL = *(const uint4*)(qrow + off_);                                   \
        VL = *(const uint4*)(vrow + off_);                                   \
        int vi_ = i0 + 2 * (t + (P));                                        \
        IDR = edge_src[min(vi_ + 14, last)];                                 \
        f32x2 qf_[4], vf_[4];                                                \
        up2x4(QW, qf_);                                                      \
        up2x4(VW, vf_);                                                      \
        f32x2 d_ = qf_[0] * kf2[0];                                          \
        d_ += qf_[1] * kf2[1];                                               \
        d_ += qf_[2] * kf2[2];                                               \
        d_ += qf_[3] * kf2[3];                                               \
        float s_ = d_.x + d_.y;                                              \
        s_ += __shfl_xor(s_, 1);                                             \
        s_ += __shfl_xor(s_, 2);                                             \
        bool ok_ = vi_ < end;                                                \
        float sc_ = ok_ ? s_ * SC : -1e30f;                                  \
        float mn_ = fmaxf(m, sc_);                                           \
        float w_ = exp2f(sc_ - mn_);                                         \
        w_ = ok_ ? w_ : 0.0f;                                                \
        float al_ = exp2f(m - mn_);                                          \
        zsum = zsum * al_ + w_;                                              \
        f32x2 a2_ = {al_, al_}, w2_ = {w_, w_};                              \
        af2[0] = af2[0] * a2_ + vf_[0] * w2_;                                \
        af2[1] = af2[1] * a2_ + vf_[1] * w2_;                                \
        af2[2] = af2[2] * a2_ + vf_[2] * w2_;                                \
        af2[3] = af2[3] * a2_ + vf_[3] * w2_;                                \
        m = mn_;                                                             \
    } while (0)

    for (int t = 0; t < U; t += 4) {
        BODY(qA, vA, qD, vD, id3, 0);   // compute t+0, load slot t+3
        BODY(qB, vB, qA, vA, id4, 1);   // compute t+1, load slot t+4
        BODY(qC, vC, qB, vB, id5, 2);   // compute t+2, load slot t+5
        BODY(qD, vD, qC, vC, id6, 3);   // compute t+3, load slot t+6
    }
#undef BODY

    // combine halves: rescale to common max, sum across lane^32
    float mo = __shfl_xor(m, 32);
    float mt = fmaxf(m, mo);
    float scale = exp2f(m - mt);       // empty half: exp2(-1e30 - mt) = 0
    zsum *= scale;
    zsum += __shfl_xor(zsum, 32);
    #pragma unroll
    for (int j = 0; j < 4; j++) {
        af2[j].x = af2[j].x * scale;
        af2[j].y = af2[j].y * scale;
        af2[j].x += __shfl_xor(af2[j].x, 32);
        af2[j].y += __shfl_xor(af2[j].y, 32);
    }

    float inv = 1.0f / fmaxf(zsum, 1e-16f);
    if (half == 0) {
        float4 o0 = {af2[0].x * inv, af2[0].y * inv, af2[1].x * inv, af2[1].y * inv};
        float4 o1 = {af2[2].x * inv, af2[2].y * inv, af2[3].x * inv, af2[3].y * inv};
        *(float4*)op = o0;
        *(float4*)(op + 4) = o1;
    }
}

// ---------------------------------------------------------------------------
extern "C" void kernel_launch(void* const* d_in, const int* in_sizes, int n_in,
                              void* d_out, int out_size, void* d_ws, size_t ws_size,
                              hipStream_t stream) {
    const float* x  = (const float*)d_in[0];
    const float* Wq = (const float*)d_in[1];
    const float* bq = (const float*)d_in[2];
    const float* Wk = (const float*)d_in[3];
    const float* bk = (const float*)d_in[4];
    const float* Wv = (const float*)d_in[5];
    const float* bv = (const float*)d_in[6];
    const int* src  = (const int*)d_in[7];
    const int* dst  = (const int*)d_in[8];
    float* out = (float*)d_out;

    unsigned short* qbf = (unsigned short*)d_ws;
    unsigned short* kbf = qbf + (size_t)N_NODES * INNER;
    unsigned short* vbf = kbf + (size_t)N_NODES * INNER;
    unsigned short* xbf = vbf + (size_t)N_NODES * INNER;
    unsigned short* Wt  = xbf + (size_t)M_PAD * INNER;
    int* deg      = (int*)(Wt + 3 * 65536);
    int* rowptr   = deg + N_NODES;
    int* edge_src = rowptr + (N_NODES + 1);

    hipMemsetAsync(deg, 0, (size_t)N_NODES * sizeof(int), stream);

    prep<<<NB_CONVX + NB_CONVW + NB_HIST, 256, 0, stream>>>(
        x, Wq, Wk, Wv, dst, xbf, Wt, deg);

    // gemm + embedded rowptr scan (block GEMM_NWG)
    gemm_qkv<<<GEMM_NWG + 1, 256, 0, stream>>>(
        xbf, Wt, bq, bk, bv, qbf, kbf, vbf, deg, rowptr);

    csr_scatter<<<(N_EDGES + 255) / 256, 256, 0, stream>>>(
        src, dst, rowptr, deg, edge_src);

    node_attn<<<(N_NODES + 3) / 4, 256, 0, stream>>>(
        qbf, kbf, vbf, rowptr, edge_src, out);
}

// Round 4
// 377.872 us; speedup vs baseline: 1.2826x; 1.2826x over previous
//
#include <hip/hip_runtime.h>
#include <math.h>

#define N_NODES 50000
#define N_EDGES 800000
#define DIM 256
#define HEADS 8
#define DIM_OUT 32
#define INNER 256        // HEADS*DIM_OUT
#define M_PAD 50048      // 391 * 128

typedef __attribute__((ext_vector_type(8))) short bf16x8;
typedef __attribute__((ext_vector_type(4))) float f32x4;
typedef __attribute__((ext_vector_type(2))) float f32x2;

// round-to-nearest-even f32 -> bf16 bits
__device__ __forceinline__ unsigned short f2bf(float f) {
    unsigned u = __float_as_uint(f);
    unsigned r = (u + 0x7FFFu + ((u >> 16) & 1u)) >> 16;
    return (unsigned short)r;
}

// unpack uint (2 packed bf16) -> f32x2
__device__ __forceinline__ f32x2 up2(unsigned u) {
    f32x2 r;
    r.x = __uint_as_float(u << 16);
    r.y = __uint_as_float(u & 0xFFFF0000u);
    return r;
}
__device__ __forceinline__ void up2x4(uint4 r, f32x2* o) {
    o[0] = up2(r.x); o[1] = up2(r.y); o[2] = up2(r.z); o[3] = up2(r.w);
}

// global -> LDS direct copy, 16 B per lane, dest = wave-uniform base + lane*16
__device__ __forceinline__ void gll16(const void* g, void* l) {
    __builtin_amdgcn_global_load_lds(
        (const __attribute__((address_space(1))) unsigned*)(uintptr_t)g,
        (__attribute__((address_space(3))) unsigned*)(unsigned)(uintptr_t)l,
        16, 0, 0);
}

// ---------------------------------------------------------------------------
// prep: conv_x (6256 blocks) + conv_w (768) + deg_hist (3125), one dispatch.
// ---------------------------------------------------------------------------
#define NB_CONVX 6256   // M_PAD*256/8/256
#define NB_CONVW 768    // 3*65536/256
#define NB_HIST  3125   // N_EDGES/256
__global__ __launch_bounds__(256) void prep(
    const float* __restrict__ x,
    const float* __restrict__ Wq, const float* __restrict__ Wk,
    const float* __restrict__ Wv,
    const int* __restrict__ dst,
    unsigned short* __restrict__ xbf, unsigned short* __restrict__ Wt,
    int* __restrict__ deg)
{
    int b = blockIdx.x;
    if (b < NB_CONVX) {
        size_t i8 = ((size_t)b * 256 + threadIdx.x) * 8;
        unsigned short h[8];
        if (i8 < (size_t)N_NODES * 256) {
            float4 a = *(const float4*)(x + i8);
            float4 c = *(const float4*)(x + i8 + 4);
            h[0]=f2bf(a.x); h[1]=f2bf(a.y); h[2]=f2bf(a.z); h[3]=f2bf(a.w);
            h[4]=f2bf(c.x); h[5]=f2bf(c.y); h[6]=f2bf(c.z); h[7]=f2bf(c.w);
        } else {
            #pragma unroll
            for (int j = 0; j < 8; j++) h[j] = 0;
        }
        uint4 o;
        o.x = (unsigned)h[0] | ((unsigned)h[1] << 16);
        o.y = (unsigned)h[2] | ((unsigned)h[3] << 16);
        o.z = (unsigned)h[4] | ((unsigned)h[5] << 16);
        o.w = (unsigned)h[6] | ((unsigned)h[7] << 16);
        *(uint4*)(xbf + i8) = o;
    } else if (b < NB_CONVX + NB_CONVW) {
        int idx = (b - NB_CONVX) * 256 + threadIdx.x;   // < 3*65536
        int z = idx >> 16, r = idx & 65535;
        int k = r >> 8, n = r & 255;
        const float* W = (z == 0) ? Wq : (z == 1) ? Wk : Wv;
        Wt[(size_t)z * 65536 + n * 256 + k] = f2bf(W[k * 256 + n]);
    } else {
        int e = (b - NB_CONVX - NB_CONVW) * 256 + threadIdx.x;
        if (e < N_EDGES) atomicAdd(deg + dst[e], 1);
    }
}

// ---------------------------------------------------------------------------
// Fused QKV GEMM: bf16 MFMA 16x16x32, 128x128 tile, BK=32 (R2-proven),
// m97-style staging via global_load_lds (width 16). XCD-chunked bijective
// remap (m204) keeps the 6 blocks sharing an A row-panel on one XCD's L2.
// q and v epilogues write INTERLEAVED records qv[node][0..255|256..511] so
// node_attn's per-edge q+v gather hits one contiguous 1 KB block.
// Block GEMM_NWG (one extra) runs the rowptr scan concurrently (scan needs
// only deg from prep; gemm only xbf/Wt) -> scan dispatch disappears.
// ---------------------------------------------------------------------------
#define GEMM_NWG 2346   // 391 * 2 * 3
__global__ __launch_bounds__(256) void gemm_qkv(
    const unsigned short* __restrict__ xbf,
    const unsigned short* __restrict__ Wt,   // [3][n][k] bf16
    const float* __restrict__ bq, const float* __restrict__ bk,
    const float* __restrict__ bv,
    unsigned short* __restrict__ qv, unsigned short* __restrict__ kbf,
    const int* __restrict__ deg, int* __restrict__ rowptr)
{
    const int t = threadIdx.x;

    if (blockIdx.x == GEMM_NWG) {
        // ---- embedded single-block scan (256 threads, 1024-int tiles) ----
        __shared__ int wsum4[4];
        __shared__ int wpre4[5];
        int wid = t >> 6, ln = t & 63;
        int carry = 0;
        for (int base = 0; base < N_NODES; base += 1024) {
            int i4 = base + t * 4;
            int4 dv = {0, 0, 0, 0};
            if (i4 < N_NODES) dv = *(const int4*)(deg + i4);  // N_NODES%4==0
            int sum = dv.x + dv.y + dv.z + dv.w;
            int inc = sum;
            #pragma unroll
            for (int off = 1; off < 64; off <<= 1) {
                int u = __shfl_up(inc, off);
                if (ln >= off) inc += u;
            }
            if (ln == 63) wsum4[wid] = inc;
            __syncthreads();
            if (t == 0) {
                int a = 0;
                #pragma unroll
                for (int j = 0; j < 4; j++) { wpre4[j] = a; a += wsum4[j]; }
                wpre4[4] = a;
            }
            __syncthreads();
            if (i4 < N_NODES) {
                int r = carry + wpre4[wid] + (inc - sum);
                r += dv.x; rowptr[i4 + 1] = r;
                r += dv.y; rowptr[i4 + 2] = r;
                r += dv.z; rowptr[i4 + 3] = r;
                r += dv.w; rowptr[i4 + 4] = r;
            }
            carry += wpre4[4];
            __syncthreads();        // protect wsum4 for next tile
        }
        if (t == 0) rowptr[0] = 0;
        return;
    }

    // XCD-chunked bijective remap (nwg=2346: q8=293, r8=2)
    int hw = blockIdx.x;
    int xcd = hw & 7, pos = hw >> 3;
    const int q8 = GEMM_NWG >> 3, r8 = GEMM_NWG & 7;
    int lid = (xcd < r8 ? xcd * (q8 + 1) : r8 * (q8 + 1) + (xcd - r8) * q8) + pos;
    int xx = lid / 6;               // A row-panel index (slowest)
    int yz = lid - xx * 6;
    const int row0 = xx * 128;
    const int col0 = (yz & 1) * 128;
    const int z = yz >> 1;

    const unsigned short* Wz = Wt + (size_t)z * 65536;
    const float* bias = (z == 0) ? bq : (z == 1) ? bk : bv;
    // output target: q -> qv[...][0..255], v -> qv[...][256..511], k -> kbf
    unsigned short* C = (z == 1) ? kbf : (qv + ((z == 0) ? 0 : 256));
    const int cstride = (z == 1) ? 256 : 512;

    __shared__ __align__(16) short As[128 * 32];
    __shared__ __align__(16) short Bs[128 * 32];

    const int wave = t >> 6;
    const int lane = t & 63;
    const int wm = (wave & 1) * 64;
    const int wn = (wave >> 1) * 64;
    const int lr = lane & 15;
    const int lg = lane >> 4;
    const int srow = lane >> 2;       // staging: row within 16-row segment
    const int sch  = lane & 3;        // staging: 16-B chunk within row

    f32x4 acc[4][4] = {};

    for (int k0 = 0; k0 < 256; k0 += 32) {
        #pragma unroll
        for (int c = 0; c < 2; c++) {
            int seg = wave * 2 + c;
            gll16(xbf + (size_t)(row0 + seg * 16 + srow) * 256 + k0 + sch * 8,
                  As + seg * 512);      // 512 shorts = 16 rows * 32
        }
        #pragma unroll
        for (int c = 0; c < 2; c++) {
            int seg = wave * 2 + c;
            gll16(Wz + (size_t)(col0 + seg * 16 + srow) * 256 + k0 + sch * 8,
                  Bs + seg * 512);
        }
        __syncthreads();   // compiler emits vmcnt(0) drain before s_barrier

        bf16x8 af[4], bfr[4];
        #pragma unroll
        for (int mi = 0; mi < 4; mi++)
            af[mi] = *(const bf16x8*)&As[(wm + mi * 16 + lr) * 32 + lg * 8];
        #pragma unroll
        for (int ni = 0; ni < 4; ni++)
            bfr[ni] = *(const bf16x8*)&Bs[(wn + ni * 16 + lr) * 32 + lg * 8];
        #pragma unroll
        for (int mi = 0; mi < 4; mi++)
            #pragma unroll
            for (int ni = 0; ni < 4; ni++)
                acc[mi][ni] = __builtin_amdgcn_mfma_f32_16x16x32_bf16(
                    af[mi], bfr[ni], acc[mi][ni], 0, 0, 0);
        __syncthreads();
    }

    // epilogue: C/D layout col=lane&15, row=(lane>>4)*4+reg  [m89-verified]
    #pragma unroll
    for (int mi = 0; mi < 4; mi++) {
        #pragma unroll
        for (int ni = 0; ni < 4; ni++) {
            int gcol = col0 + wn + ni * 16 + lr;
            float bb = bias[gcol];
            #pragma unroll
            for (int r = 0; r < 4; r++) {
                int grow = row0 + wm + mi * 16 + lg * 4 + r;
                if (grow < N_NODES)
                    C[(size_t)grow * cstride + gcol] = f2bf(acc[mi][ni][r] + bb);
            }
        }
    }
}

// csr_scatter consumes deg via atomicSub (deg dead after scan).
// Payload is src[e] directly — node_attn then needs NO src[] indirection.
__global__ __launch_bounds__(256) void csr_scatter(
    const int* __restrict__ src, const int* __restrict__ dst,
    const int* __restrict__ rowptr,
    int* __restrict__ deg, int* __restrict__ edge_src)
{
    int e = blockIdx.x * 256 + threadIdx.x;
    if (e >= N_EDGES) return;
    int d = dst[e];
    int old = atomicSub(deg + d, 1);      // old in [1..degree]
    edge_src[rowptr[d] + old - 1] = src[e];
}

// ---------------------------------------------------------------------------
// Fused single-pass attention per dst node. One wave per node, half-wave per
// edge stream (32 lanes x 8 bf16 = 256 dims). Flash-style online softmax in
// exp2 domain. Wave-uniform counted loop; period-3 rotation (R2-proven:
// VGPR 52, no spill, no launch-bounds cap). q|v interleaved records: both
// per-edge gathers land in one contiguous 1 KB block.
// ---------------------------------------------------------------------------
__global__ __launch_bounds__(256) void node_attn(
    const unsigned short* __restrict__ qv,
    const unsigned short* __restrict__ kbf,
    const int* __restrict__ rowptr, const int* __restrict__ edge_src,
    float* __restrict__ out)
{
    int node = blockIdx.x * 4 + (threadIdx.x >> 6);
    int lane = threadIdx.x & 63;
    if (node >= N_NODES) return;
    const int half = lane >> 5;
    const int l = lane & 31;

    int beg = rowptr[node], end = rowptr[node + 1];
    int deg = end - beg;

    float* op = out + (size_t)node * 256 + l * 8;
    if (deg <= 0) {               // no incoming edges -> zeros (matches ref)
        if (half == 0) {
            float4 z4 = {0.f, 0.f, 0.f, 0.f};
            *(float4*)op = z4;
            *(float4*)(op + 4) = z4;
        }
        return;
    }

    f32x2 kf2[4];
    up2x4(*(const uint4*)(kbf + (size_t)node * 256 + l * 8), kf2);

    const unsigned short* qrow = qv + l * 8;         // + id*512 shorts
    const unsigned short* vrow = qv + 256 + l * 8;   // + id*512 shorts

    // 1/sqrt(32) * log2(e): softmax runs in exp2 domain (ratios exact)
    const float SC = 0.17677669529663687f * 1.4426950408889634f;

    int U = (deg + 1) >> 1;            // slots per half (half1 may have -1)
    U = ((U + 2) / 3) * 3;             // round up to unroll factor 3
    U = __builtin_amdgcn_readfirstlane(U);   // wave-uniform -> scalar loop

    const int i0 = beg + half;         // this half's stream, stride 2
    const int last = end - 1;          // clamp target (valid: deg >= 1)

    // ramp: rows for slots 0,1; ids for slots 2,3 (slot 4 fetched by body0)
    int tmp0 = edge_src[min(i0,     last)];
    int tmp1 = edge_src[min(i0 + 2, last)];
    int idC  = edge_src[min(i0 + 4, last)];
    int idA  = edge_src[min(i0 + 6, last)];
    int idB  = 0;
    uint4 qA = *(const uint4*)(qrow + (size_t)tmp0 * 512);
    uint4 vA = *(const uint4*)(vrow + (size_t)tmp0 * 512);
    uint4 qB = *(const uint4*)(qrow + (size_t)tmp1 * 512);
    uint4 vB = *(const uint4*)(vrow + (size_t)tmp1 * 512);
    uint4 qC, vC;

    float m = -1e30f, zsum = 0.0f;
    f32x2 af2[4] = {};

// body for slot t+P: compute from (QW,VW); load rows of slot t+P+2 into
// (QL,VL) via IDL; fetch id of slot t+P+4 into IDF.
#define BODY(QW, VW, QL, VL, IDL, IDF, P)                                    \
    do {                                                                     \
        size_t off_ = (size_t)(IDL) * 512;                                   \
        QL = *(const uint4*)(qrow + off_);                                   \
        VL = *(const uint4*)(vrow + off_);                                   \
        int vi_ = i0 + 2 * t + 2 * (P);                                      \
        IDF = edge_src[min(vi_ + 8, last)];                                  \
        f32x2 qf_[4], vf_[4];                                                \
        up2x4(QW, qf_);                                                      \
        up2x4(VW, vf_);                                                      \
        f32x2 d_ = qf_[0] * kf2[0];                                          \
        d_ += qf_[1] * kf2[1];                                               \
        d_ += qf_[2] * kf2[2];                                               \
        d_ += qf_[3] * kf2[3];                                               \
        float s_ = d_.x + d_.y;                                              \
        s_ += __shfl_xor(s_, 1);                                             \
        s_ += __shfl_xor(s_, 2);                                             \
        bool ok_ = vi_ < end;                                                \
        float sc_ = ok_ ? s_ * SC : -1e30f;                                  \
        float mn_ = fmaxf(m, sc_);                                           \
        float w_ = exp2f(sc_ - mn_);                                         \
        w_ = ok_ ? w_ : 0.0f;                                                \
        float al_ = exp2f(m - mn_);                                          \
        zsum = zsum * al_ + w_;                                              \
        f32x2 a2_ = {al_, al_}, w2_ = {w_, w_};                              \
        af2[0] = af2[0] * a2_ + vf_[0] * w2_;                                \
        af2[1] = af2[1] * a2_ + vf_[1] * w2_;                                \
        af2[2] = af2[2] * a2_ + vf_[2] * w2_;                                \
        af2[3] = af2[3] * a2_ + vf_[3] * w2_;                                \
        m = mn_;                                                             \
    } while (0)

    for (int t = 0; t < U; t += 3) {
        BODY(qA, vA, qC, vC, idC, idB, 0);
        BODY(qB, vB, qA, vA, idA, idC, 1);
        BODY(qC, vC, qB, vB, idB, idA, 2);
    }
#undef BODY

    // combine halves: rescale to common max, sum across lane^32
    float mo = __shfl_xor(m, 32);
    float mt = fmaxf(m, mo);
    float scale = exp2f(m - mt);       // empty half: exp2(-1e30 - mt) = 0
    zsum *= scale;
    zsum += __shfl_xor(zsum, 32);
    #pragma unroll
    for (int j = 0; j < 4; j++) {
        af2[j].x = af2[j].x * scale;
        af2[j].y = af2[j].y * scale;
        af2[j].x += __shfl_xor(af2[j].x, 32);
        af2[j].y += __shfl_xor(af2[j].y, 32);
    }

    float inv = 1.0f / fmaxf(zsum, 1e-16f);
    if (half == 0) {
        float4 o0 = {af2[0].x * inv, af2[0].y * inv, af2[1].x * inv, af2[1].y * inv};
        float4 o1 = {af2[2].x * inv, af2[2].y * inv, af2[3].x * inv, af2[3].y * inv};
        *(float4*)op = o0;
        *(float4*)(op + 4) = o1;
    }
}

// ---------------------------------------------------------------------------
extern "C" void kernel_launch(void* const* d_in, const int* in_sizes, int n_in,
                              void* d_out, int out_size, void* d_ws, size_t ws_size,
                              hipStream_t stream) {
    const float* x  = (const float*)d_in[0];
    const float* Wq = (const float*)d_in[1];
    const float* bq = (const float*)d_in[2];
    const float* Wk = (const float*)d_in[3];
    const float* bk = (const float*)d_in[4];
    const float* Wv = (const float*)d_in[5];
    const float* bv = (const float*)d_in[6];
    const int* src  = (const int*)d_in[7];
    const int* dst  = (const int*)d_in[8];
    float* out = (float*)d_out;

    unsigned short* qv  = (unsigned short*)d_ws;           // [N][512] q|v
    unsigned short* kbf = qv + (size_t)N_NODES * 512;      // [N][256]
    unsigned short* xbf = kbf + (size_t)N_NODES * 256;     // [M_PAD][256]
    unsigned short* Wt  = xbf + (size_t)M_PAD * 256;       // 3*65536
    int* deg      = (int*)(Wt + 3 * 65536);
    int* rowptr   = deg + N_NODES;
    int* edge_src = rowptr + (N_NODES + 1);

    hipMemsetAsync(deg, 0, (size_t)N_NODES * sizeof(int), stream);

    prep<<<NB_CONVX + NB_CONVW + NB_HIST, 256, 0, stream>>>(
        x, Wq, Wk, Wv, dst, xbf, Wt, deg);

    // gemm + embedded rowptr scan (block GEMM_NWG)
    gemm_qkv<<<GEMM_NWG + 1, 256, 0, stream>>>(
        xbf, Wt, bq, bk, bv, qv, kbf, deg, rowptr);

    csr_scatter<<<(N_EDGES + 255) / 256, 256, 0, stream>>>(
        src, dst, rowptr, deg, edge_src);

    node_attn<<<(N_NODES + 3) / 4, 256, 0, stream>>>(
        qv, kbf, rowptr, edge_src, out);
}

// Round 5
// 366.414 us; speedup vs baseline: 1.3227x; 1.0313x over previous
//
#include <hip/hip_runtime.h>
#include <math.h>

#define N_NODES 50000
#define N_EDGES 800000
#define DIM 256
#define HEADS 8
#define DIM_OUT 32
#define INNER 256        // HEADS*DIM_OUT
#define M_PAD 50048      // 391 * 128

typedef __attribute__((ext_vector_type(8))) short bf16x8;
typedef __attribute__((ext_vector_type(4))) float f32x4;
typedef __attribute__((ext_vector_type(2))) float f32x2;

// round-to-nearest-even f32 -> bf16 bits
__device__ __forceinline__ unsigned short f2bf(float f) {
    unsigned u = __float_as_uint(f);
    unsigned r = (u + 0x7FFFu + ((u >> 16) & 1u)) >> 16;
    return (unsigned short)r;
}

// unpack uint (2 packed bf16) -> f32x2
__device__ __forceinline__ f32x2 up2(unsigned u) {
    f32x2 r;
    r.x = __uint_as_float(u << 16);
    r.y = __uint_as_float(u & 0xFFFF0000u);
    return r;
}
__device__ __forceinline__ void up2x4(uint4 r, f32x2* o) {
    o[0] = up2(r.x); o[1] = up2(r.y); o[2] = up2(r.z); o[3] = up2(r.w);
}

// global -> LDS direct copy, 16 B per lane, dest = wave-uniform base + lane*16
__device__ __forceinline__ void gll16(const void* g, void* l) {
    __builtin_amdgcn_global_load_lds(
        (const __attribute__((address_space(1))) unsigned*)(uintptr_t)g,
        (__attribute__((address_space(3))) unsigned*)(unsigned)(uintptr_t)l,
        16, 0, 0);
}

// ---------------------------------------------------------------------------
// prep: conv_x (6256 blocks) + conv_w (768) + deg_hist (3125), one dispatch.
// ---------------------------------------------------------------------------
#define NB_CONVX 6256   // M_PAD*256/8/256
#define NB_CONVW 768    // 3*65536/256
#define NB_HIST  3125   // N_EDGES/256
__global__ __launch_bounds__(256) void prep(
    const float* __restrict__ x,
    const float* __restrict__ Wq, const float* __restrict__ Wk,
    const float* __restrict__ Wv,
    const int* __restrict__ dst,
    unsigned short* __restrict__ xbf, unsigned short* __restrict__ Wt,
    int* __restrict__ deg)
{
    int b = blockIdx.x;
    if (b < NB_CONVX) {
        size_t i8 = ((size_t)b * 256 + threadIdx.x) * 8;
        unsigned short h[8];
        if (i8 < (size_t)N_NODES * 256) {
            float4 a = *(const float4*)(x + i8);
            float4 c = *(const float4*)(x + i8 + 4);
            h[0]=f2bf(a.x); h[1]=f2bf(a.y); h[2]=f2bf(a.z); h[3]=f2bf(a.w);
            h[4]=f2bf(c.x); h[5]=f2bf(c.y); h[6]=f2bf(c.z); h[7]=f2bf(c.w);
        } else {
            #pragma unroll
            for (int j = 0; j < 8; j++) h[j] = 0;
        }
        uint4 o;
        o.x = (unsigned)h[0] | ((unsigned)h[1] << 16);
        o.y = (unsigned)h[2] | ((unsigned)h[3] << 16);
        o.z = (unsigned)h[4] | ((unsigned)h[5] << 16);
        o.w = (unsigned)h[6] | ((unsigned)h[7] << 16);
        *(uint4*)(xbf + i8) = o;
    } else if (b < NB_CONVX + NB_CONVW) {
        int idx = (b - NB_CONVX) * 256 + threadIdx.x;   // < 3*65536
        int z = idx >> 16, r = idx & 65535;
        int k = r >> 8, n = r & 255;
        const float* W = (z == 0) ? Wq : (z == 1) ? Wk : Wv;
        Wt[(size_t)z * 65536 + n * 256 + k] = f2bf(W[k * 256 + n]);
    } else {
        int e = (b - NB_CONVX - NB_CONVW) * 256 + threadIdx.x;
        if (e < N_EDGES) atomicAdd(deg + dst[e], 1);
    }
}

// ---------------------------------------------------------------------------
// Fused QKV GEMM: bf16 MFMA 16x16x32, 128x128 tile, BK=32 (R2-proven),
// m97-style staging via global_load_lds (width 16). XCD-chunked bijective
// remap (m204) keeps the 6 blocks sharing an A row-panel on one XCD's L2.
// ---------------------------------------------------------------------------
#define GEMM_NWG 2346   // 391 * 2 * 3
__global__ __launch_bounds__(256) void gemm_qkv(
    const unsigned short* __restrict__ xbf,
    const unsigned short* __restrict__ Wt,   // [3][n][k] bf16
    const float* __restrict__ bq, const float* __restrict__ bk,
    const float* __restrict__ bv,
    unsigned short* __restrict__ q, unsigned short* __restrict__ k,
    unsigned short* __restrict__ v)
{
    // XCD-chunked bijective remap (nwg=2346: q8=293, r8=2)
    int hw = blockIdx.x;
    int xcd = hw & 7, pos = hw >> 3;
    const int q8 = GEMM_NWG >> 3, r8 = GEMM_NWG & 7;
    int lid = (xcd < r8 ? xcd * (q8 + 1) : r8 * (q8 + 1) + (xcd - r8) * q8) + pos;
    int xx = lid / 6;               // A row-panel index (slowest)
    int yz = lid - xx * 6;
    const int row0 = xx * 128;
    const int col0 = (yz & 1) * 128;
    const int z = yz >> 1;

    const int t = threadIdx.x;
    const unsigned short* Wz = Wt + (size_t)z * 65536;
    const float* bias = (z == 0) ? bq : (z == 1) ? bk : bv;
    unsigned short* C = (z == 0) ? q : (z == 1) ? k : v;

    __shared__ __align__(16) short As[128 * 32];
    __shared__ __align__(16) short Bs[128 * 32];

    const int wave = t >> 6;
    const int lane = t & 63;
    const int wm = (wave & 1) * 64;
    const int wn = (wave >> 1) * 64;
    const int lr = lane & 15;
    const int lg = lane >> 4;
    const int srow = lane >> 2;       // staging: row within 16-row segment
    const int sch  = lane & 3;        // staging: 16-B chunk within row

    f32x4 acc[4][4] = {};

    for (int k0 = 0; k0 < 256; k0 += 32) {
        #pragma unroll
        for (int c = 0; c < 2; c++) {
            int seg = wave * 2 + c;
            gll16(xbf + (size_t)(row0 + seg * 16 + srow) * 256 + k0 + sch * 8,
                  As + seg * 512);      // 512 shorts = 16 rows * 32
        }
        #pragma unroll
        for (int c = 0; c < 2; c++) {
            int seg = wave * 2 + c;
            gll16(Wz + (size_t)(col0 + seg * 16 + srow) * 256 + k0 + sch * 8,
                  Bs + seg * 512);
        }
        __syncthreads();   // compiler emits vmcnt(0) drain before s_barrier

        bf16x8 af[4], bfr[4];
        #pragma unroll
        for (int mi = 0; mi < 4; mi++)
            af[mi] = *(const bf16x8*)&As[(wm + mi * 16 + lr) * 32 + lg * 8];
        #pragma unroll
        for (int ni = 0; ni < 4; ni++)
            bfr[ni] = *(const bf16x8*)&Bs[(wn + ni * 16 + lr) * 32 + lg * 8];
        #pragma unroll
        for (int mi = 0; mi < 4; mi++)
            #pragma unroll
            for (int ni = 0; ni < 4; ni++)
                acc[mi][ni] = __builtin_amdgcn_mfma_f32_16x16x32_bf16(
                    af[mi], bfr[ni], acc[mi][ni], 0, 0, 0);
        __syncthreads();
    }

    // epilogue: C/D layout col=lane&15, row=(lane>>4)*4+reg  [m89-verified]
    #pragma unroll
    for (int mi = 0; mi < 4; mi++) {
        #pragma unroll
        for (int ni = 0; ni < 4; ni++) {
            int gcol = col0 + wn + ni * 16 + lr;
            float bb = bias[gcol];
            #pragma unroll
            for (int r = 0; r < 4; r++) {
                int grow = row0 + wm + mi * 16 + lg * 4 + r;
                if (grow < N_NODES)
                    C[(size_t)grow * 256 + gcol] = f2bf(acc[mi][ni][r] + bb);
            }
        }
    }
}

// ---------------------------------------------------------------------------
// Single-block scan, wave-shuffle version (R2-proven): 3 barriers/tile.
// ---------------------------------------------------------------------------
__global__ __launch_bounds__(1024) void scan_deg(
    const int* __restrict__ deg, int* __restrict__ rowptr)
{
    __shared__ int wsum[16];
    __shared__ int wpre[16];
    int t = threadIdx.x;
    int wid = t >> 6, ln = t & 63;
    int carry = 0;
    for (int base = 0; base < N_NODES; base += 4096) {
        int i4 = base + t * 4;
        int4 dv = {0, 0, 0, 0};
        if (i4 < N_NODES) dv = *(const int4*)(deg + i4);  // N_NODES%4==0
        int sum = dv.x + dv.y + dv.z + dv.w;
        int inc = sum;
        #pragma unroll
        for (int off = 1; off < 64; off <<= 1) {
            int u = __shfl_up(inc, off);
            if (ln >= off) inc += u;
        }
        if (ln == 63) wsum[wid] = inc;
        __syncthreads();                       // (1) wsum visible
        if (wid == 0 && ln < 16) {
            int s = wsum[ln];
            int p = s;
            #pragma unroll
            for (int off = 1; off < 16; off <<= 1) {
                int u = __shfl_up(p, off);
                if (ln >= off) p += u;
            }
            wpre[ln] = p - s;                  // exclusive wave prefix
        }
        __syncthreads();                       // (2) wpre visible
        if (i4 < N_NODES) {
            int r = carry + wpre[wid] + (inc - sum);   // exclusive prefix
            r += dv.x; rowptr[i4 + 1] = r;
            r += dv.y; rowptr[i4 + 2] = r;
            r += dv.z; rowptr[i4 + 3] = r;
            r += dv.w; rowptr[i4 + 4] = r;
        }
        carry += wpre[15] + wsum[15];          // block total
        __syncthreads();                       // (3) protect wsum for next tile
    }
    if (t == 0) rowptr[0] = 0;
}

// csr_scatter consumes deg via atomicSub (deg dead after scan).
// Payload is src[e] directly — node_attn then needs NO src[] indirection.
__global__ __launch_bounds__(256) void csr_scatter(
    const int* __restrict__ src, const int* __restrict__ dst,
    const int* __restrict__ rowptr,
    int* __restrict__ deg, int* __restrict__ edge_src)
{
    int e = blockIdx.x * 256 + threadIdx.x;
    if (e >= N_EDGES) return;
    int d = dst[e];
    int old = atomicSub(deg + d, 1);      // old in [1..degree]
    edge_src[rowptr[d] + old - 1] = src[e];
}

// ---------------------------------------------------------------------------
// Fused single-pass attention per dst node. One wave per node. R5: FOUR edge
// streams per wave (2 register-streams x 2 lane-halves, stride 4), each with
// period-3 rotating buffers: 6 rows (12 gathers) in flight per wave -> ~3x
// outstanding misses vs R2 (MLP theory: latency-bound, not BW-bound).
// Natural register allocation (NO min-waves launch-bounds clause - R3 lesson:
// the cap caused spill). Flash online softmax in exp2 domain; wave-uniform
// counted loop; clamped addresses + branchless neutralization.
// Stream (h,s) covers edge indices beg + h + 2s + 4t.
// ---------------------------------------------------------------------------
__global__ __launch_bounds__(256) void node_attn(
    const unsigned short* __restrict__ qbf,
    const unsigned short* __restrict__ kbf,
    const unsigned short* __restrict__ vbf,
    const int* __restrict__ rowptr, const int* __restrict__ edge_src,
    float* __restrict__ out)
{
    int node = blockIdx.x * 4 + (threadIdx.x >> 6);
    int lane = threadIdx.x & 63;
    if (node >= N_NODES) return;
    const int half = lane >> 5;
    const int l = lane & 31;

    int beg = rowptr[node], end = rowptr[node + 1];
    int deg = end - beg;

    float* op = out + (size_t)node * 256 + l * 8;
    if (deg <= 0) {               // no incoming edges -> zeros (matches ref)
        if (half == 0) {
            float4 z4 = {0.f, 0.f, 0.f, 0.f};
            *(float4*)op = z4;
            *(float4*)(op + 4) = z4;
        }
        return;
    }

    f32x2 kf2[4];
    up2x4(*(const uint4*)(kbf + (size_t)node * 256 + l * 8), kf2);

    const unsigned short* qrow = qbf + l * 8;   // + id*256 shorts per edge
    const unsigned short* vrow = vbf + l * 8;

    // 1/sqrt(32) * log2(e): softmax runs in exp2 domain (ratios exact)
    const float SC = 0.17677669529663687f * 1.4426950408889634f;

    int U = (deg + 3) >> 2;            // max bodies over the 4 streams
    U = ((U + 2) / 3) * 3;             // round up to period-3
    U = __builtin_amdgcn_readfirstlane(U);   // wave-uniform -> scalar loop

    const int last = end - 1;          // clamp target (valid: deg >= 1)
    const int i0 = beg + half;         // stream0: edges i0 + 4t
    const int i1 = beg + half + 2;     // stream1: edges i1 + 4t

    // ---- ramp: rows for slots 0,1; ids for slots 2,3 (per stream) ----
    int r00 = edge_src[min(i0,      last)];
    int r01 = edge_src[min(i0 + 4,  last)];
    int idC0 = edge_src[min(i0 + 8,  last)];
    int idA0 = edge_src[min(i0 + 12, last)];
    int idB0 = 0;
    int r10 = edge_src[min(i1,      last)];
    int r11 = edge_src[min(i1 + 4,  last)];
    int idC1 = edge_src[min(i1 + 8,  last)];
    int idA1 = edge_src[min(i1 + 12, last)];
    int idB1 = 0;

    uint4 qA0 = *(const uint4*)(qrow + (size_t)r00 * 256);
    uint4 vA0 = *(const uint4*)(vrow + (size_t)r00 * 256);
    uint4 qA1 = *(const uint4*)(qrow + (size_t)r10 * 256);
    uint4 vA1 = *(const uint4*)(vrow + (size_t)r10 * 256);
    uint4 qB0 = *(const uint4*)(qrow + (size_t)r01 * 256);
    uint4 vB0 = *(const uint4*)(vrow + (size_t)r01 * 256);
    uint4 qB1 = *(const uint4*)(qrow + (size_t)r11 * 256);
    uint4 vB1 = *(const uint4*)(vrow + (size_t)r11 * 256);
    uint4 qC0, vC0, qC1, vC1;

    float m0 = -1e30f, z0 = 0.0f, m1 = -1e30f, z1 = 0.0f;
    f32x2 af0[4] = {}, af1[4] = {};

// issue rows of slot t+P+2 (via IDL) and fetch id of slot t+P+4 into IDF
#define LOADP(I0S, QL, VL, IDL, IDF, P)                                      \
    do {                                                                     \
        size_t off_ = (size_t)(IDL) * 256;                                   \
        QL = *(const uint4*)(qrow + off_);                                   \
        VL = *(const uint4*)(vrow + off_);                                   \
        IDF = edge_src[min((I0S) + 4 * (t + (P)) + 16, last)];               \
    } while (0)

// consume rows of slot t+P from (QW,VW) into stream state (M,Z,AF)
#define COMPP(I0S, M, Z, AF, QW, VW, P)                                      \
    do {                                                                     \
        f32x2 qf_[4], vf_[4];                                                \
        up2x4(QW, qf_);                                                      \
        up2x4(VW, vf_);                                                      \
        f32x2 d_ = qf_[0] * kf2[0];                                          \
        d_ += qf_[1] * kf2[1];                                               \
        d_ += qf_[2] * kf2[2];                                               \
        d_ += qf_[3] * kf2[3];                                               \
        float s_ = d_.x + d_.y;                                              \
        s_ += __shfl_xor(s_, 1);                                             \
        s_ += __shfl_xor(s_, 2);                                             \
        int vi_ = (I0S) + 4 * (t + (P));                                     \
        bool ok_ = vi_ < end;                                                \
        float sc_ = ok_ ? s_ * SC : -1e30f;                                  \
        float mn_ = fmaxf(M, sc_);                                           \
        float w_ = exp2f(sc_ - mn_);                                         \
        w_ = ok_ ? w_ : 0.0f;                                                \
        float al_ = exp2f(M - mn_);                                          \
        Z = Z * al_ + w_;                                                    \
        f32x2 a2_ = {al_, al_}, w2_ = {w_, w_};                              \
        AF[0] = AF[0] * a2_ + vf_[0] * w2_;                                  \
        AF[1] = AF[1] * a2_ + vf_[1] * w2_;                                  \
        AF[2] = AF[2] * a2_ + vf_[2] * w2_;                                  \
        AF[3] = AF[3] * a2_ + vf_[3] * w2_;                                  \
        M = mn_;                                                             \
    } while (0)

    for (int t = 0; t < U; t += 3) {
        // P=0: compute A, load C, fetch idB
        LOADP(i0, qC0, vC0, idC0, idB0, 0);
        LOADP(i1, qC1, vC1, idC1, idB1, 0);
        COMPP(i0, m0, z0, af0, qA0, vA0, 0);
        COMPP(i1, m1, z1, af1, qA1, vA1, 0);
        // P=1: compute B, load A, fetch idC
        LOADP(i0, qA0, vA0, idA0, idC0, 1);
        LOADP(i1, qA1, vA1, idA1, idC1, 1);
        COMPP(i0, m0, z0, af0, qB0, vB0, 1);
        COMPP(i1, m1, z1, af1, qB1, vB1, 1);
        // P=2: compute C, load B, fetch idA
        LOADP(i0, qB0, vB0, idB0, idA0, 2);
        LOADP(i1, qB1, vB1, idB1, idA1, 2);
        COMPP(i0, m0, z0, af0, qC0, vC0, 2);
        COMPP(i1, m1, z1, af1, qC1, vC1, 2);
    }
#undef LOADP
#undef COMPP

    // ---- merge register-streams (in-register, no shuffles) ----
    // empty-stream safety: m=-1e30, z=0, af=0 -> contributes 0 (exp2(0)*0)
    float mm = fmaxf(m0, m1);
    float c0 = exp2f(m0 - mm);
    float c1 = exp2f(m1 - mm);
    float zsum = z0 * c0 + z1 * c1;
    f32x2 af2[4];
    f32x2 c02 = {c0, c0}, c12 = {c1, c1};
    #pragma unroll
    for (int j = 0; j < 4; j++) af2[j] = af0[j] * c02 + af1[j] * c12;

    // ---- combine halves: rescale to common max, sum across lane^32 ----
    float mo = __shfl_xor(mm, 32);
    float mt = fmaxf(mm, mo);
    float scale = exp2f(mm - mt);      // empty half: z=af=0 -> harmless
    zsum *= scale;
    zsum += __shfl_xor(zsum, 32);
    #pragma unroll
    for (int j = 0; j < 4; j++) {
        af2[j].x = af2[j].x * scale;
        af2[j].y = af2[j].y * scale;
        af2[j].x += __shfl_xor(af2[j].x, 32);
        af2[j].y += __shfl_xor(af2[j].y, 32);
    }

    float inv = 1.0f / fmaxf(zsum, 1e-16f);
    if (half == 0) {
        float4 o0 = {af2[0].x * inv, af2[0].y * inv, af2[1].x * inv, af2[1].y * inv};
        float4 o1 = {af2[2].x * inv, af2[2].y * inv, af2[3].x * inv, af2[3].y * inv};
        *(float4*)op = o0;
        *(float4*)(op + 4) = o1;
    }
}

// ---------------------------------------------------------------------------
extern "C" void kernel_launch(void* const* d_in, const int* in_sizes, int n_in,
                              void* d_out, int out_size, void* d_ws, size_t ws_size,
                              hipStream_t stream) {
    const float* x  = (const float*)d_in[0];
    const float* Wq = (const float*)d_in[1];
    const float* bq = (const float*)d_in[2];
    const float* Wk = (const float*)d_in[3];
    const float* bk = (const float*)d_in[4];
    const float* Wv = (const float*)d_in[5];
    const float* bv = (const float*)d_in[6];
    const int* src  = (const int*)d_in[7];
    const int* dst  = (const int*)d_in[8];
    float* out = (float*)d_out;

    unsigned short* qbf = (unsigned short*)d_ws;
    unsigned short* kbf = qbf + (size_t)N_NODES * INNER;
    unsigned short* vbf = kbf + (size_t)N_NODES * INNER;
    unsigned short* xbf = vbf + (size_t)N_NODES * INNER;
    unsigned short* Wt  = xbf + (size_t)M_PAD * INNER;
    int* deg      = (int*)(Wt + 3 * 65536);
    int* rowptr   = deg + N_NODES;
    int* edge_src = rowptr + (N_NODES + 1);

    hipMemsetAsync(deg, 0, (size_t)N_NODES * sizeof(int), stream);

    prep<<<NB_CONVX + NB_CONVW + NB_HIST, 256, 0, stream>>>(
        x, Wq, Wk, Wv, dst, xbf, Wt, deg);

    gemm_qkv<<<GEMM_NWG, 256, 0, stream>>>(xbf, Wt, bq, bk, bv, qbf, kbf, vbf);

    scan_deg<<<1, 1024, 0, stream>>>(deg, rowptr);
    csr_scatter<<<(N_EDGES + 255) / 256, 256, 0, stream>>>(
        src, dst, rowptr, deg, edge_src);

    node_attn<<<(N_NODES + 3) / 4, 256, 0, stream>>>(
        qbf, kbf, vbf, rowptr, edge_src, out);
}

// Round 6
// 359.971 us; speedup vs baseline: 1.3464x; 1.0179x over previous
//
#include <hip/hip_runtime.h>
#include <math.h>

#define N_NODES 50000
#define N_EDGES 800000
#define DIM 256
#define HEADS 8
#define DIM_OUT 32
#define INNER 256        // HEADS*DIM_OUT
#define M_PAD 50048      // 391 * 128

typedef __attribute__((ext_vector_type(8))) short bf16x8;
typedef __attribute__((ext_vector_type(4))) float f32x4;
typedef __attribute__((ext_vector_type(2))) float f32x2;

// round-to-nearest-even f32 -> bf16 bits
__device__ __forceinline__ unsigned short f2bf(float f) {
    unsigned u = __float_as_uint(f);
    unsigned r = (u + 0x7FFFu + ((u >> 16) & 1u)) >> 16;
    return (unsigned short)r;
}

// unpack uint (2 packed bf16) -> f32x2
__device__ __forceinline__ f32x2 up2(unsigned u) {
    f32x2 r;
    r.x = __uint_as_float(u << 16);
    r.y = __uint_as_float(u & 0xFFFF0000u);
    return r;
}
__device__ __forceinline__ void up2x4(uint4 r, f32x2* o) {
    o[0] = up2(r.x); o[1] = up2(r.y); o[2] = up2(r.z); o[3] = up2(r.w);
}

// global -> LDS direct copy, 16 B per lane, dest = wave-uniform base + lane*16
__device__ __forceinline__ void gll16(const void* g, void* l) {
    __builtin_amdgcn_global_load_lds(
        (const __attribute__((address_space(1))) unsigned*)(uintptr_t)g,
        (__attribute__((address_space(3))) unsigned*)(unsigned)(uintptr_t)l,
        16, 0, 0);
}

// ---------------------------------------------------------------------------
// prep: conv_x (6256 blocks) + conv_w (768) + deg_hist (3125), one dispatch.
// ---------------------------------------------------------------------------
#define NB_CONVX 6256   // M_PAD*256/8/256
#define NB_CONVW 768    // 3*65536/256
#define NB_HIST  3125   // N_EDGES/256
__global__ __launch_bounds__(256) void prep(
    const float* __restrict__ x,
    const float* __restrict__ Wq, const float* __restrict__ Wk,
    const float* __restrict__ Wv,
    const int* __restrict__ dst,
    unsigned short* __restrict__ xbf, unsigned short* __restrict__ Wt,
    int* __restrict__ deg)
{
    int b = blockIdx.x;
    if (b < NB_CONVX) {
        size_t i8 = ((size_t)b * 256 + threadIdx.x) * 8;
        unsigned short h[8];
        if (i8 < (size_t)N_NODES * 256) {
            float4 a = *(const float4*)(x + i8);
            float4 c = *(const float4*)(x + i8 + 4);
            h[0]=f2bf(a.x); h[1]=f2bf(a.y); h[2]=f2bf(a.z); h[3]=f2bf(a.w);
            h[4]=f2bf(c.x); h[5]=f2bf(c.y); h[6]=f2bf(c.z); h[7]=f2bf(c.w);
        } else {
            #pragma unroll
            for (int j = 0; j < 8; j++) h[j] = 0;
        }
        uint4 o;
        o.x = (unsigned)h[0] | ((unsigned)h[1] << 16);
        o.y = (unsigned)h[2] | ((unsigned)h[3] << 16);
        o.z = (unsigned)h[4] | ((unsigned)h[5] << 16);
        o.w = (unsigned)h[6] | ((unsigned)h[7] << 16);
        *(uint4*)(xbf + i8) = o;
    } else if (b < NB_CONVX + NB_CONVW) {
        int idx = (b - NB_CONVX) * 256 + threadIdx.x;   // < 3*65536
        int z = idx >> 16, r = idx & 65535;
        int k = r >> 8, n = r & 255;
        const float* W = (z == 0) ? Wq : (z == 1) ? Wk : Wv;
        Wt[(size_t)z * 65536 + n * 256 + k] = f2bf(W[k * 256 + n]);
    } else {
        int e = (b - NB_CONVX - NB_CONVW) * 256 + threadIdx.x;
        if (e < N_EDGES) atomicAdd(deg + dst[e], 1);
    }
}

// ---------------------------------------------------------------------------
// Fused QKV GEMM, R6 shape: BM=128 x BN=256 (full N), BK=32, 512 threads =
// 8 waves (2M x 4N, each wave 64x64 out). vs R2's 128x128: halves block
// count (1173 vs 2346), halves A-panel re-reads (3 z-blocks per panel,
// adjacent in swizzled id-space -> same XCD L2), halves per-output drain /
// prologue / epilogue overhead. LDS 8+16=24 KB -> 4 blocks/CU.
// m97-style staging via global_load_lds (width 16), single-buffered.
// ---------------------------------------------------------------------------
#define GEMM_NWG 1173   // 391 panels * 3 z
__global__ __launch_bounds__(512) void gemm_qkv(
    const unsigned short* __restrict__ xbf,
    const unsigned short* __restrict__ Wt,   // [3][n][k] bf16
    const float* __restrict__ bq, const float* __restrict__ bk,
    const float* __restrict__ bv,
    unsigned short* __restrict__ q, unsigned short* __restrict__ k,
    unsigned short* __restrict__ v)
{
    // XCD-chunked bijective remap (nwg=1173: q8=146, r8=5)
    int hw = blockIdx.x;
    int xcd = hw & 7, pos = hw >> 3;
    int lid = (xcd < 5 ? xcd * 147 : 5 * 147 + (xcd - 5) * 146) + pos;
    int panel = lid / 3;            // A row-panel index (z fastest)
    int z = lid - panel * 3;
    const int row0 = panel * 128;

    const int t = threadIdx.x;
    const unsigned short* Wz = Wt + (size_t)z * 65536;
    const float* bias = (z == 0) ? bq : (z == 1) ? bk : bv;
    unsigned short* C = (z == 0) ? q : (z == 1) ? k : v;

    __shared__ __align__(16) short As[128 * 32];   // 8 KB
    __shared__ __align__(16) short Bs[256 * 32];   // 16 KB

    const int wave = t >> 6;          // 0..7
    const int lane = t & 63;
    const int wm = (wave & 1) * 64;
    const int wn = (wave >> 1) * 64;  // 0,64,128,192
    const int lr = lane & 15;
    const int lg = lane >> 4;
    const int srow = lane >> 2;       // staging: row within 16-row segment
    const int sch  = lane & 3;        // staging: 16-B chunk within row

    f32x4 acc[4][4] = {};

    for (int k0 = 0; k0 < 256; k0 += 32) {
        // A: 128 rows x 32 k = 8 segments of 16 rows; wave w stages seg w
        gll16(xbf + (size_t)(row0 + wave * 16 + srow) * 256 + k0 + sch * 8,
              As + wave * 512);       // 512 shorts = 16 rows * 32
        // B: 256 rows x 32 k = 16 segments; wave w stages segs 2w, 2w+1
        #pragma unroll
        for (int c = 0; c < 2; c++) {
            gll16(Wz + (size_t)(wave * 32 + c * 16 + srow) * 256 + k0 + sch * 8,
                  Bs + wave * 1024 + c * 512);
        }
        __syncthreads();   // compiler emits vmcnt(0) drain before s_barrier

        bf16x8 af[4], bfr[4];
        #pragma unroll
        for (int mi = 0; mi < 4; mi++)
            af[mi] = *(const bf16x8*)&As[(wm + mi * 16 + lr) * 32 + lg * 8];
        #pragma unroll
        for (int ni = 0; ni < 4; ni++)
            bfr[ni] = *(const bf16x8*)&Bs[(wn + ni * 16 + lr) * 32 + lg * 8];
        #pragma unroll
        for (int mi = 0; mi < 4; mi++)
            #pragma unroll
            for (int ni = 0; ni < 4; ni++)
                acc[mi][ni] = __builtin_amdgcn_mfma_f32_16x16x32_bf16(
                    af[mi], bfr[ni], acc[mi][ni], 0, 0, 0);
        __syncthreads();
    }

    // epilogue: C/D layout col=lane&15, row=(lane>>4)*4+reg  [m89-verified]
    #pragma unroll
    for (int mi = 0; mi < 4; mi++) {
        #pragma unroll
        for (int ni = 0; ni < 4; ni++) {
            int gcol = wn + ni * 16 + lr;
            float bb = bias[gcol];
            #pragma unroll
            for (int r = 0; r < 4; r++) {
                int grow = row0 + wm + mi * 16 + lg * 4 + r;
                if (grow < N_NODES)
                    C[(size_t)grow * 256 + gcol] = f2bf(acc[mi][ni][r] + bb);
            }
        }
    }
}

// ---------------------------------------------------------------------------
// Single-block scan, wave-shuffle version (R2-proven): 3 barriers/tile.
// ---------------------------------------------------------------------------
__global__ __launch_bounds__(1024) void scan_deg(
    const int* __restrict__ deg, int* __restrict__ rowptr)
{
    __shared__ int wsum[16];
    __shared__ int wpre[16];
    int t = threadIdx.x;
    int wid = t >> 6, ln = t & 63;
    int carry = 0;
    for (int base = 0; base < N_NODES; base += 4096) {
        int i4 = base + t * 4;
        int4 dv = {0, 0, 0, 0};
        if (i4 < N_NODES) dv = *(const int4*)(deg + i4);  // N_NODES%4==0
        int sum = dv.x + dv.y + dv.z + dv.w;
        int inc = sum;
        #pragma unroll
        for (int off = 1; off < 64; off <<= 1) {
            int u = __shfl_up(inc, off);
            if (ln >= off) inc += u;
        }
        if (ln == 63) wsum[wid] = inc;
        __syncthreads();                       // (1) wsum visible
        if (wid == 0 && ln < 16) {
            int s = wsum[ln];
            int p = s;
            #pragma unroll
            for (int off = 1; off < 16; off <<= 1) {
                int u = __shfl_up(p, off);
                if (ln >= off) p += u;
            }
            wpre[ln] = p - s;                  // exclusive wave prefix
        }
        __syncthreads();                       // (2) wpre visible
        if (i4 < N_NODES) {
            int r = carry + wpre[wid] + (inc - sum);   // exclusive prefix
            r += dv.x; rowptr[i4 + 1] = r;
            r += dv.y; rowptr[i4 + 2] = r;
            r += dv.z; rowptr[i4 + 3] = r;
            r += dv.w; rowptr[i4 + 4] = r;
        }
        carry += wpre[15] + wsum[15];          // block total
        __syncthreads();                       // (3) protect wsum for next tile
    }
    if (t == 0) rowptr[0] = 0;
}

// csr_scatter consumes deg via atomicSub (deg dead after scan).
// Payload is src[e] directly — node_attn then needs NO src[] indirection.
__global__ __launch_bounds__(256) void csr_scatter(
    const int* __restrict__ src, const int* __restrict__ dst,
    const int* __restrict__ rowptr,
    int* __restrict__ deg, int* __restrict__ edge_src)
{
    int e = blockIdx.x * 256 + threadIdx.x;
    if (e >= N_EDGES) return;
    int d = dst[e];
    int old = atomicSub(deg + d, 1);      // old in [1..degree]
    edge_src[rowptr[d] + old - 1] = src[e];
}

// ---------------------------------------------------------------------------
// Fused single-pass attention per dst node (R2-proven exact structure:
// 116.4 us, VGPR 52). One wave per node, half-wave per edge stream. Flash
// online softmax in exp2 domain; wave-uniform counted loop; period-3
// rotating buffers (rows 2 ahead, ids 4 ahead); clamped addresses with
// branchless neutralization. Gather path is throughput-saturated (R5
// established: more MLP does not help), so minimize VALU instead.
// ---------------------------------------------------------------------------
__global__ __launch_bounds__(256) void node_attn(
    const unsigned short* __restrict__ qbf,
    const unsigned short* __restrict__ kbf,
    const unsigned short* __restrict__ vbf,
    const int* __restrict__ rowptr, const int* __restrict__ edge_src,
    float* __restrict__ out)
{
    int node = blockIdx.x * 4 + (threadIdx.x >> 6);
    int lane = threadIdx.x & 63;
    if (node >= N_NODES) return;
    const int half = lane >> 5;
    const int l = lane & 31;

    int beg = rowptr[node], end = rowptr[node + 1];
    int deg = end - beg;

    float* op = out + (size_t)node * 256 + l * 8;
    if (deg <= 0) {               // no incoming edges -> zeros (matches ref)
        if (half == 0) {
            float4 z4 = {0.f, 0.f, 0.f, 0.f};
            *(float4*)op = z4;
            *(float4*)(op + 4) = z4;
        }
        return;
    }

    f32x2 kf2[4];
    up2x4(*(const uint4*)(kbf + (size_t)node * 256 + l * 8), kf2);

    const unsigned short* qrow = qbf + l * 8;   // + id*256 shorts per edge
    const unsigned short* vrow = vbf + l * 8;

    // 1/sqrt(32) * log2(e): softmax runs in exp2 domain (ratios exact)
    const float SC = 0.17677669529663687f * 1.4426950408889634f;

    int U = (deg + 1) >> 1;            // slots per half (half1 may have -1)
    U = ((U + 2) / 3) * 3;             // round up to unroll factor 3
    U = __builtin_amdgcn_readfirstlane(U);   // wave-uniform -> scalar loop

    const int i0 = beg + half;         // this half's stream, stride 2
    const int last = end - 1;          // clamp target (valid: deg >= 1)

    // ramp: rows for slots 0,1; ids for slots 2,3 (slot 4 fetched by body0)
    int tmp0 = edge_src[min(i0,     last)];
    int tmp1 = edge_src[min(i0 + 2, last)];
    int idC  = edge_src[min(i0 + 4, last)];
    int idA  = edge_src[min(i0 + 6, last)];
    int idB  = 0;
    uint4 qA = *(const uint4*)(qrow + (size_t)tmp0 * 256);
    uint4 vA = *(const uint4*)(vrow + (size_t)tmp0 * 256);
    uint4 qB = *(const uint4*)(qrow + (size_t)tmp1 * 256);
    uint4 vB = *(const uint4*)(vrow + (size_t)tmp1 * 256);
    uint4 qC, vC;

    float m = -1e30f, zsum = 0.0f;
    f32x2 af2[4] = {};

// body for slot t+P: compute from (QW,VW); load rows of slot t+P+2 into
// (QL,VL) via IDL; fetch id of slot t+P+4 into IDF.
#define BODY(QW, VW, QL, VL, IDL, IDF, P)                                    \
    do {                                                                     \
        size_t off_ = (size_t)(IDL) * 256;                                   \
        QL = *(const uint4*)(qrow + off_);                                   \
        VL = *(const uint4*)(vrow + off_);                                   \
        int vi_ = i0 + 2 * t + 2 * (P);                                      \
        IDF = edge_src[min(vi_ + 8, last)];                                  \
        f32x2 qf_[4], vf_[4];                                                \
        up2x4(QW, qf_);                                                      \
        up2x4(VW, vf_);                                                      \
        f32x2 d_ = qf_[0] * kf2[0];                                          \
        d_ += qf_[1] * kf2[1];                                               \
        d_ += qf_[2] * kf2[2];                                               \
        d_ += qf_[3] * kf2[3];                                               \
        float s_ = d_.x + d_.y;                                              \
        s_ += __shfl_xor(s_, 1);                                             \
        s_ += __shfl_xor(s_, 2);                                             \
        bool ok_ = vi_ < end;                                                \
        float sc_ = ok_ ? s_ * SC : -1e30f;                                  \
        float mn_ = fmaxf(m, sc_);                                           \
        float w_ = exp2f(sc_ - mn_);                                         \
        w_ = ok_ ? w_ : 0.0f;                                                \
        float al_ = exp2f(m - mn_);                                          \
        zsum = zsum * al_ + w_;                                              \
        f32x2 a2_ = {al_, al_}, w2_ = {w_, w_};                              \
        af2[0] = af2[0] * a2_ + vf_[0] * w2_;                                \
        af2[1] = af2[1] * a2_ + vf_[1] * w2_;                                \
        af2[2] = af2[2] * a2_ + vf_[2] * w2_;                                \
        af2[3] = af2[3] * a2_ + vf_[3] * w2_;                                \
        m = mn_;                                                             \
    } while (0)

    for (int t = 0; t < U; t += 3) {
        BODY(qA, vA, qC, vC, idC, idB, 0);
        BODY(qB, vB, qA, vA, idA, idC, 1);
        BODY(qC, vC, qB, vB, idB, idA, 2);
    }
#undef BODY

    // combine halves: rescale to common max, sum across lane^32
    float mo = __shfl_xor(m, 32);
    float mt = fmaxf(m, mo);
    float scale = exp2f(m - mt);       // empty half: exp2(-1e30 - mt) = 0
    zsum *= scale;
    zsum += __shfl_xor(zsum, 32);
    #pragma unroll
    for (int j = 0; j < 4; j++) {
        af2[j].x = af2[j].x * scale;
        af2[j].y = af2[j].y * scale;
        af2[j].x += __shfl_xor(af2[j].x, 32);
        af2[j].y += __shfl_xor(af2[j].y, 32);
    }

    float inv = 1.0f / fmaxf(zsum, 1e-16f);
    if (half == 0) {
        float4 o0 = {af2[0].x * inv, af2[0].y * inv, af2[1].x * inv, af2[1].y * inv};
        float4 o1 = {af2[2].x * inv, af2[2].y * inv, af2[3].x * inv, af2[3].y * inv};
        *(float4*)op = o0;
        *(float4*)(op + 4) = o1;
    }
}

// ---------------------------------------------------------------------------
extern "C" void kernel_launch(void* const* d_in, const int* in_sizes, int n_in,
                              void* d_out, int out_size, void* d_ws, size_t ws_size,
                              hipStream_t stream) {
    const float* x  = (const float*)d_in[0];
    const float* Wq = (const float*)d_in[1];
    const float* bq = (const float*)d_in[2];
    const float* Wk = (const float*)d_in[3];
    const float* bk = (const float*)d_in[4];
    const float* Wv = (const float*)d_in[5];
    const float* bv = (const float*)d_in[6];
    const int* src  = (const int*)d_in[7];
    const int* dst  = (const int*)d_in[8];
    float* out = (float*)d_out;

    unsigned short* qbf = (unsigned short*)d_ws;
    unsigned short* kbf = qbf + (size_t)N_NODES * INNER;
    unsigned short* vbf = kbf + (size_t)N_NODES * INNER;
    unsigned short* xbf = vbf + (size_t)N_NODES * INNER;
    unsigned short* Wt  = xbf + (size_t)M_PAD * INNER;
    int* deg      = (int*)(Wt + 3 * 65536);
    int* rowptr   = deg + N_NODES;
    int* edge_src = rowptr + (N_NODES + 1);

    hipMemsetAsync(deg, 0, (size_t)N_NODES * sizeof(int), stream);

    prep<<<NB_CONVX + NB_CONVW + NB_HIST, 256, 0, stream>>>(
        x, Wq, Wk, Wv, dst, xbf, Wt, deg);

    gemm_qkv<<<GEMM_NWG, 512, 0, stream>>>(xbf, Wt, bq, bk, bv, qbf, kbf, vbf);

    scan_deg<<<1, 1024, 0, stream>>>(deg, rowptr);
    csr_scatter<<<(N_EDGES + 255) / 256, 256, 0, stream>>>(
        src, dst, rowptr, deg, edge_src);

    node_attn<<<(N_NODES + 3) / 4, 256, 0, stream>>>(
        qbf, kbf, vbf, rowptr, edge_src, out);
}

// Round 7
// 325.383 us; speedup vs baseline: 1.4895x; 1.1063x over previous
//
#include <hip/hip_runtime.h>
#include <math.h>

#define N_NODES 50000
#define N_EDGES 800000
#define DIM 256
#define HEADS 8
#define DIM_OUT 32
#define INNER 256        // HEADS*DIM_OUT
#define M_PAD 50048      // 391 * 128

typedef __attribute__((ext_vector_type(8))) short bf16x8;
typedef __attribute__((ext_vector_type(4))) float f32x4;
typedef __attribute__((ext_vector_type(2))) float f32x2;

// round-to-nearest-even f32 -> bf16 bits
__device__ __forceinline__ unsigned short f2bf(float f) {
    unsigned u = __float_as_uint(f);
    unsigned r = (u + 0x7FFFu + ((u >> 16) & 1u)) >> 16;
    return (unsigned short)r;
}

// unpack uint (2 packed bf16) -> f32x2
__device__ __forceinline__ f32x2 up2(unsigned u) {
    f32x2 r;
    r.x = __uint_as_float(u << 16);
    r.y = __uint_as_float(u & 0xFFFF0000u);
    return r;
}
__device__ __forceinline__ void up2x4(uint4 r, f32x2* o) {
    o[0] = up2(r.x); o[1] = up2(r.y); o[2] = up2(r.z); o[3] = up2(r.w);
}

// global -> LDS direct copy, 16 B per lane, dest = wave-uniform base + lane*16
__device__ __forceinline__ void gll16(const void* g, void* l) {
    __builtin_amdgcn_global_load_lds(
        (const __attribute__((address_space(1))) unsigned*)(uintptr_t)g,
        (__attribute__((address_space(3))) unsigned*)(unsigned)(uintptr_t)l,
        16, 0, 0);
}

// ---------------------------------------------------------------------------
// prep: conv_x (6256 blocks) + conv_w (768) + deg_hist+rank (3125), one
// dispatch. The histogram's atomicAdd return value IS the edge's rank within
// its dst bucket -> stored to rank[] so csr_scatter needs no atomics.
// ---------------------------------------------------------------------------
#define NB_CONVX 6256   // M_PAD*256/8/256
#define NB_CONVW 768    // 3*65536/256
#define NB_HIST  3125   // N_EDGES/256
__global__ __launch_bounds__(256) void prep(
    const float* __restrict__ x,
    const float* __restrict__ Wq, const float* __restrict__ Wk,
    const float* __restrict__ Wv,
    const int* __restrict__ dst,
    unsigned short* __restrict__ xbf, unsigned short* __restrict__ Wt,
    int* __restrict__ deg, int* __restrict__ rank)
{
    int b = blockIdx.x;
    if (b < NB_CONVX) {
        size_t i8 = ((size_t)b * 256 + threadIdx.x) * 8;
        unsigned short h[8];
        if (i8 < (size_t)N_NODES * 256) {
            float4 a = *(const float4*)(x + i8);
            float4 c = *(const float4*)(x + i8 + 4);
            h[0]=f2bf(a.x); h[1]=f2bf(a.y); h[2]=f2bf(a.z); h[3]=f2bf(a.w);
            h[4]=f2bf(c.x); h[5]=f2bf(c.y); h[6]=f2bf(c.z); h[7]=f2bf(c.w);
        } else {
            #pragma unroll
            for (int j = 0; j < 8; j++) h[j] = 0;
        }
        uint4 o;
        o.x = (unsigned)h[0] | ((unsigned)h[1] << 16);
        o.y = (unsigned)h[2] | ((unsigned)h[3] << 16);
        o.z = (unsigned)h[4] | ((unsigned)h[5] << 16);
        o.w = (unsigned)h[6] | ((unsigned)h[7] << 16);
        *(uint4*)(xbf + i8) = o;
    } else if (b < NB_CONVX + NB_CONVW) {
        int idx = (b - NB_CONVX) * 256 + threadIdx.x;   // < 3*65536
        int z = idx >> 16, r = idx & 65535;
        int k = r >> 8, n = r & 255;
        const float* W = (z == 0) ? Wq : (z == 1) ? Wk : Wv;
        Wt[(size_t)z * 65536 + n * 256 + k] = f2bf(W[k * 256 + n]);
    } else {
        int e = (b - NB_CONVX - NB_CONVW) * 256 + threadIdx.x;
        if (e < N_EDGES) rank[e] = atomicAdd(deg + dst[e], 1);
    }
}

// ---------------------------------------------------------------------------
// Fused QKV GEMM, BM=128 x BN=256, BK=32, 512 threads (8 waves, 2Mx4N),
// DOUBLE-BUFFERED LDS (T3-minimum 2-phase): stage tile s+1 after the barrier,
// before computing tile s; ONE barrier per K-step. The vmcnt(0) drain at the
// next loop-top lands after a full MFMA phase -> staging latency hidden.
// Hazard note: barrier at step i guarantees all waves' LDS reads of the
// buffer being overwritten completed (syncthreads waits lgkmcnt(0)).
// LDS 2x24=48 KB -> 3 blocks/CU. XCD-chunked bijective remap (m204).
// Block 0 runs the rowptr scan CONCURRENTLY (dispatched FIRST - R3's mistake
// was putting it last, making it a straggler); it finishes under gemm.
// ---------------------------------------------------------------------------
#define GEMM_NWG 1173   // 391 panels * 3 z
__global__ __launch_bounds__(512) void gemm_qkv(
    const unsigned short* __restrict__ xbf,
    const unsigned short* __restrict__ Wt,   // [3][n][k] bf16
    const float* __restrict__ bq, const float* __restrict__ bk,
    const float* __restrict__ bv,
    unsigned short* __restrict__ q, unsigned short* __restrict__ k,
    unsigned short* __restrict__ v,
    const int* __restrict__ deg, int* __restrict__ rowptr)
{
    const int t = threadIdx.x;

    if (blockIdx.x == 0) {
        // ---- embedded rowptr scan: 512 threads, 2048-int tiles, 25 tiles ----
        __shared__ int wsum[8];
        __shared__ int wpre[9];
        int wid = t >> 6, ln = t & 63;
        int carry = 0;
        for (int base = 0; base < N_NODES; base += 2048) {
            int i4 = base + t * 4;
            int4 dv = {0, 0, 0, 0};
            if (i4 < N_NODES) dv = *(const int4*)(deg + i4);  // N_NODES%4==0
            int sum = dv.x + dv.y + dv.z + dv.w;
            int inc = sum;
            #pragma unroll
            for (int off = 1; off < 64; off <<= 1) {
                int u = __shfl_up(inc, off);
                if (ln >= off) inc += u;
            }
            if (ln == 63) wsum[wid] = inc;
            __syncthreads();
            if (t == 0) {
                int a = 0;
                #pragma unroll
                for (int j = 0; j < 8; j++) { wpre[j] = a; a += wsum[j]; }
                wpre[8] = a;
            }
            __syncthreads();
            if (i4 < N_NODES) {
                int r = carry + wpre[wid] + (inc - sum);
                r += dv.x; rowptr[i4 + 1] = r;
                r += dv.y; rowptr[i4 + 2] = r;
                r += dv.z; rowptr[i4 + 3] = r;
                r += dv.w; rowptr[i4 + 4] = r;
            }
            carry += wpre[8];
            __syncthreads();        // protect wsum for next tile
        }
        if (t == 0) rowptr[0] = 0;
        return;
    }

    // XCD-chunked bijective remap over the 1173 gemm blocks (q8=146, r8=5)
    int hw = blockIdx.x - 1;
    int xcd = hw & 7, pos = hw >> 3;
    int lid = (xcd < 5 ? xcd * 147 : 5 * 147 + (xcd - 5) * 146) + pos;
    int panel = lid / 3;            // A row-panel index (z fastest)
    int z = lid - panel * 3;
    const int row0 = panel * 128;

    const unsigned short* Wz = Wt + (size_t)z * 65536;
    const float* bias = (z == 0) ? bq : (z == 1) ? bk : bv;
    unsigned short* C = (z == 0) ? q : (z == 1) ? k : v;

    __shared__ __align__(16) short As[2][128 * 32];   // 8 KB x2
    __shared__ __align__(16) short Bs[2][256 * 32];   // 16 KB x2

    const int wave = t >> 6;          // 0..7
    const int lane = t & 63;
    const int wm = (wave & 1) * 64;
    const int wn = (wave >> 1) * 64;  // 0,64,128,192
    const int lr = lane & 15;
    const int lg = lane >> 4;
    const int srow = lane >> 2;       // staging: row within 16-row segment
    const int sch  = lane & 3;        // staging: 16-B chunk within row

    f32x4 acc[4][4] = {};

// stage K-tile at col K into buffer B: A seg 'wave' (16 rows), B segs 2w,2w+1
#define STAGE(B, K)                                                          \
    do {                                                                     \
        gll16(xbf + (size_t)(row0 + wave * 16 + srow) * 256 + (K) + sch * 8, \
              &As[B][wave * 512]);                                           \
        gll16(Wz + (size_t)(wave * 32 + srow) * 256 + (K) + sch * 8,         \
              &Bs[B][wave * 1024]);                                          \
        gll16(Wz + (size_t)(wave * 32 + 16 + srow) * 256 + (K) + sch * 8,    \
              &Bs[B][wave * 1024 + 512]);                                    \
    } while (0)

    STAGE(0, 0);
    #pragma unroll
    for (int s = 0; s < 8; s++) {
        const int cur = s & 1;
        __syncthreads();              // drains stage for buffer cur
        if (s < 7) STAGE(cur ^ 1, (s + 1) * 32);   // overlaps with MFMA below
        bf16x8 af[4], bfr[4];
        #pragma unroll
        for (int mi = 0; mi < 4; mi++)
            af[mi] = *(const bf16x8*)&As[cur][(wm + mi * 16 + lr) * 32 + lg * 8];
        #pragma unroll
        for (int ni = 0; ni < 4; ni++)
            bfr[ni] = *(const bf16x8*)&Bs[cur][(wn + ni * 16 + lr) * 32 + lg * 8];
        #pragma unroll
        for (int mi = 0; mi < 4; mi++)
            #pragma unroll
            for (int ni = 0; ni < 4; ni++)
                acc[mi][ni] = __builtin_amdgcn_mfma_f32_16x16x32_bf16(
                    af[mi], bfr[ni], acc[mi][ni], 0, 0, 0);
    }
#undef STAGE

    // epilogue: C/D layout col=lane&15, row=(lane>>4)*4+reg  [m89-verified]
    #pragma unroll
    for (int mi = 0; mi < 4; mi++) {
        #pragma unroll
        for (int ni = 0; ni < 4; ni++) {
            int gcol = wn + ni * 16 + lr;
            float bb = bias[gcol];
            #pragma unroll
            for (int r = 0; r < 4; r++) {
                int grow = row0 + wm + mi * 16 + lg * 4 + r;
                if (grow < N_NODES)
                    C[(size_t)grow * 256 + gcol] = f2bf(acc[mi][ni][r] + bb);
            }
        }
    }
}

// csr_scatter, atomic-free: rank[e] (from prep's histogram return) gives the
// unique slot. Reads are coalesced; rowptr gather is 200 KB (L2-resident).
__global__ __launch_bounds__(256) void csr_scatter(
    const int* __restrict__ src, const int* __restrict__ dst,
    const int* __restrict__ rowptr, const int* __restrict__ rank,
    int* __restrict__ edge_src)
{
    int e = blockIdx.x * 256 + threadIdx.x;
    if (e >= N_EDGES) return;
    edge_src[rowptr[dst[e]] + rank[e]] = src[e];
}

// ---------------------------------------------------------------------------
// Fused single-pass attention per dst node (R2-proven exact structure:
// 116.4 us, VGPR 52). One wave per node, half-wave per edge stream. Flash
// online softmax in exp2 domain; wave-uniform counted loop; period-3
// rotating buffers (rows 2 ahead, ids 4 ahead); clamped addresses with
// branchless neutralization. Gather path is throughput-saturated (R5
// established: more MLP does not help), so minimize VALU instead.
// ---------------------------------------------------------------------------
__global__ __launch_bounds__(256) void node_attn(
    const unsigned short* __restrict__ qbf,
    const unsigned short* __restrict__ kbf,
    const unsigned short* __restrict__ vbf,
    const int* __restrict__ rowptr, const int* __restrict__ edge_src,
    float* __restrict__ out)
{
    int node = blockIdx.x * 4 + (threadIdx.x >> 6);
    int lane = threadIdx.x & 63;
    if (node >= N_NODES) return;
    const int half = lane >> 5;
    const int l = lane & 31;

    int beg = rowptr[node], end = rowptr[node + 1];
    int deg = end - beg;

    float* op = out + (size_t)node * 256 + l * 8;
    if (deg <= 0) {               // no incoming edges -> zeros (matches ref)
        if (half == 0) {
            float4 z4 = {0.f, 0.f, 0.f, 0.f};
            *(float4*)op = z4;
            *(float4*)(op + 4) = z4;
        }
        return;
    }

    f32x2 kf2[4];
    up2x4(*(const uint4*)(kbf + (size_t)node * 256 + l * 8), kf2);

    const unsigned short* qrow = qbf + l * 8;   // + id*256 shorts per edge
    const unsigned short* vrow = vbf + l * 8;

    // 1/sqrt(32) * log2(e): softmax runs in exp2 domain (ratios exact)
    const float SC = 0.17677669529663687f * 1.4426950408889634f;

    int U = (deg + 1) >> 1;            // slots per half (half1 may have -1)
    U = ((U + 2) / 3) * 3;             // round up to unroll factor 3
    U = __builtin_amdgcn_readfirstlane(U);   // wave-uniform -> scalar loop

    const int i0 = beg + half;         // this half's stream, stride 2
    const int last = end - 1;          // clamp target (valid: deg >= 1)

    // ramp: rows for slots 0,1; ids for slots 2,3 (slot 4 fetched by body0)
    int tmp0 = edge_src[min(i0,     last)];
    int tmp1 = edge_src[min(i0 + 2, last)];
    int idC  = edge_src[min(i0 + 4, last)];
    int idA  = edge_src[min(i0 + 6, last)];
    int idB  = 0;
    uint4 qA = *(const uint4*)(qrow + (size_t)tmp0 * 256);
    uint4 vA = *(const uint4*)(vrow + (size_t)tmp0 * 256);
    uint4 qB = *(const uint4*)(qrow + (size_t)tmp1 * 256);
    uint4 vB = *(const uint4*)(vrow + (size_t)tmp1 * 256);
    uint4 qC, vC;

    float m = -1e30f, zsum = 0.0f;
    f32x2 af2[4] = {};

// body for slot t+P: compute from (QW,VW); load rows of slot t+P+2 into
// (QL,VL) via IDL; fetch id of slot t+P+4 into IDF.
#define BODY(QW, VW, QL, VL, IDL, IDF, P)                                    \
    do {                                                                     \
        size_t off_ = (size_t)(IDL) * 256;                                   \
        QL = *(const uint4*)(qrow + off_);                                   \
        VL = *(const uint4*)(vrow + off_);                                   \
        int vi_ = i0 + 2 * t + 2 * (P);                                      \
        IDF = edge_src[min(vi_ + 8, last)];                                  \
        f32x2 qf_[4], vf_[4];                                                \
        up2x4(QW, qf_);                                                      \
        up2x4(VW, vf_);                                                      \
        f32x2 d_ = qf_[0] * kf2[0];                                          \
        d_ += qf_[1] * kf2[1];                                               \
        d_ += qf_[2] * kf2[2];                                               \
        d_ += qf_[3] * kf2[3];                                               \
        float s_ = d_.x + d_.y;                                              \
        s_ += __shfl_xor(s_, 1);                                             \
        s_ += __shfl_xor(s_, 2);                                             \
        bool ok_ = vi_ < end;                                                \
        float sc_ = ok_ ? s_ * SC : -1e30f;                                  \
        float mn_ = fmaxf(m, sc_);                                           \
        float w_ = exp2f(sc_ - mn_);                                         \
        w_ = ok_ ? w_ : 0.0f;                                                \
        float al_ = exp2f(m - mn_);                                          \
        zsum = zsum * al_ + w_;                                              \
        f32x2 a2_ = {al_, al_}, w2_ = {w_, w_};                              \
        af2[0] = af2[0] * a2_ + vf_[0] * w2_;                                \
        af2[1] = af2[1] * a2_ + vf_[1] * w2_;                                \
        af2[2] = af2[2] * a2_ + vf_[2] * w2_;                                \
        af2[3] = af2[3] * a2_ + vf_[3] * w2_;                                \
        m = mn_;                                                             \
    } while (0)

    for (int t = 0; t < U; t += 3) {
        BODY(qA, vA, qC, vC, idC, idB, 0);
        BODY(qB, vB, qA, vA, idA, idC, 1);
        BODY(qC, vC, qB, vB, idB, idA, 2);
    }
#undef BODY

    // combine halves: rescale to common max, sum across lane^32
    float mo = __shfl_xor(m, 32);
    float mt = fmaxf(m, mo);
    float scale = exp2f(m - mt);       // empty half: exp2(-1e30 - mt) = 0
    zsum *= scale;
    zsum += __shfl_xor(zsum, 32);
    #pragma unroll
    for (int j = 0; j < 4; j++) {
        af2[j].x = af2[j].x * scale;
        af2[j].y = af2[j].y * scale;
        af2[j].x += __shfl_xor(af2[j].x, 32);
        af2[j].y += __shfl_xor(af2[j].y, 32);
    }

    float inv = 1.0f / fmaxf(zsum, 1e-16f);
    if (half == 0) {
        float4 o0 = {af2[0].x * inv, af2[0].y * inv, af2[1].x * inv, af2[1].y * inv};
        float4 o1 = {af2[2].x * inv, af2[2].y * inv, af2[3].x * inv, af2[3].y * inv};
        *(float4*)op = o0;
        *(float4*)(op + 4) = o1;
    }
}

// ---------------------------------------------------------------------------
extern "C" void kernel_launch(void* const* d_in, const int* in_sizes, int n_in,
                              void* d_out, int out_size, void* d_ws, size_t ws_size,
                              hipStream_t stream) {
    const float* x  = (const float*)d_in[0];
    const float* Wq = (const float*)d_in[1];
    const float* bq = (const float*)d_in[2];
    const float* Wk = (const float*)d_in[3];
    const float* bk = (const float*)d_in[4];
    const float* Wv = (const float*)d_in[5];
    const float* bv = (const float*)d_in[6];
    const int* src  = (const int*)d_in[7];
    const int* dst  = (const int*)d_in[8];
    float* out = (float*)d_out;

    unsigned short* qbf = (unsigned short*)d_ws;
    unsigned short* kbf = qbf + (size_t)N_NODES * INNER;
    unsigned short* vbf = kbf + (size_t)N_NODES * INNER;
    unsigned short* xbf = vbf + (size_t)N_NODES * INNER;
    unsigned short* Wt  = xbf + (size_t)M_PAD * INNER;
    int* deg      = (int*)(Wt + 3 * 65536);
    int* rowptr   = deg + N_NODES;
    int* edge_src = rowptr + (N_NODES + 1);
    int* rank     = edge_src + N_EDGES;

    hipMemsetAsync(deg, 0, (size_t)N_NODES * sizeof(int), stream);

    prep<<<NB_CONVX + NB_CONVW + NB_HIST, 256, 0, stream>>>(
        x, Wq, Wk, Wv, dst, xbf, Wt, deg, rank);

    // gemm (blocks 1..1173) + embedded rowptr scan (block 0, runs first)
    gemm_qkv<<<GEMM_NWG + 1, 512, 0, stream>>>(
        xbf, Wt, bq, bk, bv, qbf, kbf, vbf, deg, rowptr);

    csr_scatter<<<(N_EDGES + 255) / 256, 256, 0, stream>>>(
        src, dst, rowptr, rank, edge_src);

    node_attn<<<(N_NODES + 3) / 4, 256, 0, stream>>>(
        qbf, kbf, vbf, rowptr, edge_src, out);
}